// Round 20
// baseline (151.732 us; speedup 1.0000x reference)
//
#include <hip/hip_runtime.h>
#include <hip/hip_bf16.h>

#define D_MODEL 1024
#define N_HEADS 16
#define MAX_K_LEN 1024
#define B_SZ 2
#define TQ 1024
#define TK 1024
#define M_ROWS 2048
#define NKL 16384

using bf16x8 = __attribute__((ext_vector_type(8))) short;
using f32x4  = __attribute__((ext_vector_type(4))) float;
using u16x8  = __attribute__((ext_vector_type(8))) unsigned short;

__device__ __forceinline__ unsigned short f2b(float f) {
    unsigned u = __float_as_uint(f);
    u = (u + 0x7FFFu + ((u >> 16) & 1u)) >> 16;
    return (unsigned short)u;
}
__device__ __forceinline__ float b2f(unsigned short u) {
    return __uint_as_float(((unsigned)u) << 16);
}

// async global->LDS, 16B per lane (linear LDS dest: wave base + lane*16)
__device__ __forceinline__ void async_cp16(void* lds, const void* g) {
    __builtin_amdgcn_global_load_lds(
        (__attribute__((address_space(1))) void*)(void*)g,
        (__attribute__((address_space(3))) void*)lds, 16, 0, 0);
}

// chunk swizzle for attention LDS tiles (16B-chunk permutation per 128B row)
__device__ __forceinline__ int xrow(int row) {
    return (row & 7) ^ (((row >> 3) & 3) << 1);
}

// ---------------------------------------------------------------------------
// 128x128 ptile core: BK=32, K=1024 (32 K-tiles), 256 threads = 4 waves (2x2),
// wave tile 64x64 (acc 4x4). LDS: 3 buffers x 16 KB = 48 KB -> 3 blocks/CU.
// act: 0 none, 1 exact GELU, 2 per-head Q prescale (* (1-sigmoid(gate_h))/8).
// ---------------------------------------------------------------------------
__device__ __forceinline__ void ptile128_core(
    const unsigned short* __restrict__ A, const unsigned short* __restrict__ Wt,
    const float* __restrict__ bias, unsigned short* __restrict__ C,
    int N, int m0g, int n0g, int act, const float* __restrict__ gate,
    unsigned short* lds)
{
    constexpr int NT = 32;
    const int tid = threadIdx.x;
    const int lane = tid & 63;
    const int fr = lane & 15, rg = lane >> 4;
    const int w = tid >> 6;
    const int wr = w >> 1, wc = w & 1;    // 2M x 2N waves

    const int sr = tid >> 2;              // 0..63
    const int sc = ((tid & 3) ^ ((sr >> 1) & 3)) * 8;
    const unsigned short* gA = A  + (size_t)(m0g + sr) * 1024 + sc;
    const unsigned short* gB = Wt + (size_t)(n0g + sr) * 1024 + sc;

    auto stage = [&](int t) {
        unsigned short* bufA = lds + (t % 3) * 8192;   // 16KB per buffer
        unsigned short* bufB = bufA + 4096;
        const int k0 = t * 32;
        async_cp16(bufA + tid*8,        gA + k0);
        async_cp16(bufA + 2048 + tid*8, gA + (size_t)64*1024 + k0);
        async_cp16(bufB + tid*8,        gB + k0);
        async_cp16(bufB + 2048 + tid*8, gB + (size_t)64*1024 + k0);
    };

    f32x4 acc[4][4];
#pragma unroll
    for (int i = 0; i < 4; ++i)
#pragma unroll
        for (int j = 0; j < 4; ++j) { f32x4 z = {0.f,0.f,0.f,0.f}; acc[i][j] = z; }

    const int fko = (rg ^ ((fr >> 1) & 3)) * 8;

    stage(0); stage(1);
    asm volatile("s_waitcnt vmcnt(4)" ::: "memory");
    __builtin_amdgcn_s_barrier();
    __builtin_amdgcn_sched_barrier(0);

    for (int t = 0; t < NT; ++t) {
        const unsigned short* bufA = lds + (t % 3) * 8192;
        const unsigned short* bufB = bufA + 4096;

        bf16x8 afr[4], bfr[4];
#pragma unroll
        for (int mi = 0; mi < 4; ++mi)
            afr[mi] = *(const bf16x8*)(bufA + (wr*64 + mi*16 + fr)*32 + fko);
#pragma unroll
        for (int ni = 0; ni < 4; ++ni)
            bfr[ni] = *(const bf16x8*)(bufB + (wc*64 + ni*16 + fr)*32 + fko);
        if (t + 2 < NT) stage(t + 2);

        __builtin_amdgcn_s_setprio(1);
#pragma unroll
        for (int mi = 0; mi < 4; ++mi)
#pragma unroll
            for (int ni = 0; ni < 4; ++ni)
                acc[mi][ni] = __builtin_amdgcn_mfma_f32_16x16x32_bf16(
                    afr[mi], bfr[ni], acc[mi][ni], 0, 0, 0);
        __builtin_amdgcn_s_setprio(0);

        if (t < NT - 2)       asm volatile("s_waitcnt vmcnt(4)" ::: "memory");
        else if (t == NT - 2) asm volatile("s_waitcnt vmcnt(0)" ::: "memory");
        __builtin_amdgcn_s_barrier();
        __builtin_amdgcn_sched_barrier(0);
    }

    float qs = 1.f;
    if (act == 2) {   // per-wave head constant: cols n0g+wc*64 .. +63
        const float gg = 1.f / (1.f + __expf(-gate[(n0g + wc*64) >> 6]));
        qs = (1.f - gg) * 0.125f;
    }

    unsigned short* scr = lds + w * 1024;
    float bv[4];
#pragma unroll
    for (int ni = 0; ni < 4; ++ni) bv[ni] = bias[n0g + wc*64 + ni*16 + fr];
    const int ro = lane >> 3;
    const int co = (lane & 7) * 8;
#pragma unroll
    for (int mi = 0; mi < 4; ++mi) {
#pragma unroll
        for (int ni = 0; ni < 4; ++ni)
#pragma unroll
            for (int r = 0; r < 4; ++r) {
                float c = acc[mi][ni][r] + bv[ni];
                if (act == 1) c = 0.5f * c * (1.f + erff(c * 0.70710678118654752f));
                else if (act == 2) c *= qs;
                scr[(rg*4 + r)*64 + ni*16 + fr] = f2b(c);
            }
#pragma unroll
        for (int p = 0; p < 2; ++p) {
            const int row = p*8 + ro;
            const u16x8 v = *(const u16x8*)(scr + row*64 + co);
            *(u16x8*)(C + (size_t)(m0g + wr*64 + mi*16 + row) * N + n0g + wc*64 + co) = v;
        }
    }
}

struct QkvhArgs {
    const unsigned short* A[4];
    const unsigned short* W[4];
    const float* bias[4];
    void* out[4];
    const float* gate;
};

__global__ __launch_bounds__(256, 3) void gemm_qkvh_p(QkvhArgs args) {
    __shared__ __align__(16) unsigned short lds[24576];   // 48 KB
    const int z = blockIdx.z;
    const int m0 = (blockIdx.x >> 3) * 128;
    const int n0 = (blockIdx.x & 7) * 128;
    const int act = (z == 3) ? 1 : ((z == 0) ? 2 : 0);
    ptile128_core(args.A[z], args.W[z], args.bias[z],
                  (unsigned short*)args.out[z], D_MODEL, m0, n0, act, args.gate, lds);
}

// ---------------------------------------------------------------------------
// FUSED causal logits GEMM: L = Qpre@K^T + h@Ws2g^T + bs2g, kpm+causal mask
// folded (masked -> bf16 -inf). 2-LDS-buffer variant (32 KB) -> 5 blocks/CU
// (LDS-limited): whole 1152-block grid co-resident. __launch_bounds__(256,4)
// caps VGPR at 128 >= 68 needed -> NO spill (round-18's (256,5) capped ~102
// and spilled acc to scratch). Schedule correctness HW-validated in R18.
// t=0,1 QK tiles; t=2..33 synth tiles.
// ---------------------------------------------------------------------------
__global__ __launch_bounds__(256, 4) void gemm_logits_p(
    const unsigned short* __restrict__ A, const unsigned short* __restrict__ Wt,
    const float* __restrict__ bias, unsigned short* __restrict__ C,
    const unsigned short* __restrict__ Qpre, const unsigned short* __restrict__ Kb,
    const int* __restrict__ kpm)
{
    __shared__ __align__(16) unsigned short lds[16384];   // 32 KB (2 x 16 KB)
    constexpr int NT = 34;
    const int bid = blockIdx.x;
    const int xcd = bid & 7;
    const int i = bid >> 3;                    // 0..143
    const int hi = (i >= 72) ? 1 : 0;
    const int head = xcd * 2 + hi;
    const int j = i - hi * 72;                 // 0..71
    int kq, idx;
    if (j < 16)      { kq = 0; idx = j; }
    else if (j < 30) { kq = 1; idx = j - 16; }
    else if (j < 42) { kq = 2; idx = j - 30; }
    else if (j < 52) { kq = 3; idx = j - 42; }
    else if (j < 60) { kq = 4; idx = j - 52; }
    else if (j < 66) { kq = 5; idx = j - 60; }
    else if (j < 70) { kq = 6; idx = j - 66; }
    else             { kq = 7; idx = j - 70; }
    const int b = idx & 1;
    const int rq = kq + (idx >> 1);
    const int m0g = (b * 8 + rq) * 128;        // rows in (b,q) space
    const int n0g = (head * 8 + kq) * 128;     // cols in (h,k) space

    const int tid = threadIdx.x;
    const int lane = tid & 63;
    const int fr = lane & 15, rg = lane >> 4;
    const int w = tid >> 6;
    const int wr = w >> 1, wc = w & 1;

    const int sr = tid >> 2;
    const int sc = ((tid & 3) ^ ((sr >> 1) & 3)) * 8;
    const unsigned short* gA = A  + (size_t)(m0g + sr) * 1024 + sc;
    const unsigned short* gB = Wt + (size_t)(n0g + sr) * 1024 + sc;
    const int q0 = rq * 128, k0a = kq * 128;
    const unsigned short* gA2 = Qpre + (size_t)(b*TQ + q0 + sr) * 1024 + head*64 + sc;
    const unsigned short* gB2 = Kb   + (size_t)(b*TK + k0a + sr) * 1024 + head*64 + sc;

    // stage tile t into buffer t&1. t=0,1: QK band; t>=2: synth (k0=(t-2)*32).
    auto stage = [&](int t) {
        unsigned short* bufA = lds + (t & 1) * 8192;
        unsigned short* bufB = bufA + 4096;
        const unsigned short* a;
        const unsigned short* bb;
        if (t < 2) { a = gA2 + t * 32;       bb = gB2 + t * 32; }
        else       { a = gA + (t - 2) * 32;  bb = gB + (t - 2) * 32; }
        async_cp16(bufA + tid*8,        a);
        async_cp16(bufA + 2048 + tid*8, a + (size_t)64*1024);
        async_cp16(bufB + tid*8,        bb);
        async_cp16(bufB + 2048 + tid*8, bb + (size_t)64*1024);
    };

    f32x4 acc[4][4];
#pragma unroll
    for (int ii = 0; ii < 4; ++ii)
#pragma unroll
        for (int jj = 0; jj < 4; ++jj) { f32x4 z = {0.f,0.f,0.f,0.f}; acc[ii][jj] = z; }

    const int fko = (rg ^ ((fr >> 1) & 3)) * 8;

    stage(0);
    asm volatile("s_waitcnt vmcnt(0)" ::: "memory");
    __builtin_amdgcn_s_barrier();
    __builtin_amdgcn_sched_barrier(0);

    for (int t = 0; t < NT; ++t) {
        // prefetch next tile into the other buffer (its readers completed
        // before the barrier that ended tile t-1)
        if (t + 1 < NT) stage(t + 1);

        const unsigned short* bufA = lds + (t & 1) * 8192;
        const unsigned short* bufB = bufA + 4096;

        bf16x8 afr[4], bfr[4];
#pragma unroll
        for (int mi = 0; mi < 4; ++mi)
            afr[mi] = *(const bf16x8*)(bufA + (wr*64 + mi*16 + fr)*32 + fko);
#pragma unroll
        for (int ni = 0; ni < 4; ++ni)
            bfr[ni] = *(const bf16x8*)(bufB + (wc*64 + ni*16 + fr)*32 + fko);

        __builtin_amdgcn_s_setprio(1);
#pragma unroll
        for (int mi = 0; mi < 4; ++mi)
#pragma unroll
            for (int ni = 0; ni < 4; ++ni)
                acc[mi][ni] = __builtin_amdgcn_mfma_f32_16x16x32_bf16(
                    afr[mi], bfr[ni], acc[mi][ni], 0, 0, 0);
        __builtin_amdgcn_s_setprio(0);

        // drain next tile's loads; 5 blocks/CU of cross-block overlap hides it
        asm volatile("s_waitcnt vmcnt(0)" ::: "memory");
        __builtin_amdgcn_s_barrier();
        __builtin_amdgcn_sched_barrier(0);
    }

    unsigned short* scr = lds + w * 1024;
    float bv[4];
    int kv[4];
#pragma unroll
    for (int ni = 0; ni < 4; ++ni) {
        const int colx = n0g + wc*64 + ni*16 + fr;
        bv[ni] = bias[colx];
        kv[ni] = kpm[b * TK + (colx & 1023)];
    }
    const int ro = lane >> 3;
    const int co = (lane & 7) * 8;
#pragma unroll
    for (int mi = 0; mi < 4; ++mi) {
#pragma unroll
        for (int ni = 0; ni < 4; ++ni) {
            const int k_idx = (n0g + wc*64 + ni*16 + fr) & 1023;
#pragma unroll
            for (int r = 0; r < 4; ++r) {
                const int q_idx = (m0g + wr*64 + mi*16 + rg*4 + r) & 1023;
                const bool ok = (kv[ni] > 0) && (k_idx <= q_idx);
                scr[(rg*4 + r)*64 + ni*16 + fr] =
                    ok ? f2b(acc[mi][ni][r] + bv[ni]) : (unsigned short)0xFF80u;
            }
        }
#pragma unroll
        for (int p = 0; p < 2; ++p) {
            const int row = p*8 + ro;
            const u16x8 v = *(const u16x8*)(scr + row*64 + co);
            *(u16x8*)(C + (size_t)(m0g + wr*64 + mi*16 + row) * NKL + n0g + wc*64 + co) = v;
        }
    }
}

// ---------------------------------------------------------------------------
// Out-proj: ptile128 structure, f32 direct-store epilogue. grid (8,16).
// ---------------------------------------------------------------------------
__global__ __launch_bounds__(256, 3) void gemm_out_p(
    const unsigned short* __restrict__ A, const unsigned short* __restrict__ Wt,
    const float* __restrict__ bias, float* __restrict__ C)
{
    __shared__ __align__(16) unsigned short lds[24576];   // 48 KB
    constexpr int NT = 32;
    const int m0g = blockIdx.y * 128;
    const int n0g = blockIdx.x * 128;

    const int tid = threadIdx.x;
    const int lane = tid & 63;
    const int fr = lane & 15, rg = lane >> 4;
    const int w = tid >> 6;
    const int wr = w >> 1, wc = w & 1;

    const int sr = tid >> 2;
    const int sc = ((tid & 3) ^ ((sr >> 1) & 3)) * 8;
    const unsigned short* gA = A  + (size_t)(m0g + sr) * 1024 + sc;
    const unsigned short* gB = Wt + (size_t)(n0g + sr) * 1024 + sc;

    auto stage = [&](int t) {
        unsigned short* bufA = lds + (t % 3) * 8192;
        unsigned short* bufB = bufA + 4096;
        const int k0 = t * 32;
        async_cp16(bufA + tid*8,        gA + k0);
        async_cp16(bufA + 2048 + tid*8, gA + (size_t)64*1024 + k0);
        async_cp16(bufB + tid*8,        gB + k0);
        async_cp16(bufB + 2048 + tid*8, gB + (size_t)64*1024 + k0);
    };

    f32x4 acc[4][4];
#pragma unroll
    for (int i = 0; i < 4; ++i)
#pragma unroll
        for (int j = 0; j < 4; ++j) { f32x4 z = {0.f,0.f,0.f,0.f}; acc[i][j] = z; }

    const int fko = (rg ^ ((fr >> 1) & 3)) * 8;

    stage(0); stage(1);
    asm volatile("s_waitcnt vmcnt(4)" ::: "memory");
    __builtin_amdgcn_s_barrier();
    __builtin_amdgcn_sched_barrier(0);

    for (int t = 0; t < NT; ++t) {
        const unsigned short* bufA = lds + (t % 3) * 8192;
        const unsigned short* bufB = bufA + 4096;

        bf16x8 afr[4], bfr[4];
#pragma unroll
        for (int mi = 0; mi < 4; ++mi)
            afr[mi] = *(const bf16x8*)(bufA + (wr*64 + mi*16 + fr)*32 + fko);
#pragma unroll
        for (int ni = 0; ni < 4; ++ni)
            bfr[ni] = *(const bf16x8*)(bufB + (wc*64 + ni*16 + fr)*32 + fko);
        if (t + 2 < NT) stage(t + 2);

        __builtin_amdgcn_s_setprio(1);
#pragma unroll
        for (int mi = 0; mi < 4; ++mi)
#pragma unroll
            for (int ni = 0; ni < 4; ++ni)
                acc[mi][ni] = __builtin_amdgcn_mfma_f32_16x16x32_bf16(
                    afr[mi], bfr[ni], acc[mi][ni], 0, 0, 0);
        __builtin_amdgcn_s_setprio(0);

        if (t < NT - 2)       asm volatile("s_waitcnt vmcnt(4)" ::: "memory");
        else if (t == NT - 2) asm volatile("s_waitcnt vmcnt(0)" ::: "memory");
        __builtin_amdgcn_s_barrier();
        __builtin_amdgcn_sched_barrier(0);
    }

#pragma unroll
    for (int ni = 0; ni < 4; ++ni) {
        const int colx = n0g + wc*64 + ni*16 + fr;
        const float bvv = bias[colx];
#pragma unroll
        for (int mi = 0; mi < 4; ++mi)
#pragma unroll
            for (int r = 0; r < 4; ++r) {
                const int row = m0g + wr*64 + mi*16 + rg*4 + r;
                C[(size_t)row * D_MODEL + colx] = acc[mi][ni][r] + bvv;
            }
    }
}

// ---------------------------------------------------------------------------
// fused prep: conversions + transposes + g-scaled Ws2 + g-scaled bs2.
// ---------------------------------------------------------------------------
struct PrepArgs {
    const float* xq; const float* xkv;
    unsigned short* xq_b; unsigned short* xkv_b;
    const float* W[6]; unsigned short* Wt[6]; int Nw[6];
    const float* bs2; float* bs2g; const float* gate;
};

__global__ __launch_bounds__(256) void prep_all(PrepArgs p) {
    __shared__ float T[32][33];
    int id = blockIdx.x;
    if (id < 4096) {
        const float* src = (id < 2048) ? p.xq : p.xkv;
        unsigned short* dst = (id < 2048) ? p.xq_b : p.xkv_b;
        const int i = (id & 2047) * 256 + threadIdx.x;
        const float4 v = ((const float4*)src)[i];
        ushort4 o; o.x = f2b(v.x); o.y = f2b(v.y); o.z = f2b(v.z); o.w = f2b(v.w);
        ((ushort4*)dst)[i] = o;
        return;
    }
    if (id >= 25600) {   // bs2g = sigmoid(gate) * bs2
        const int i = (id - 25600) * 256 + threadIdx.x;
        const float gg = 1.f / (1.f + __expf(-p.gate[i >> 10]));
        p.bs2g[i] = gg * p.bs2[i];
        return;
    }
    id -= 4096;
    int seg, lb;
    if (id < 5120) { seg = id >> 10; lb = id & 1023; }
    else           { seg = 5;        lb = id - 5120; }
    const int N = p.Nw[seg];
    const int nx = N >> 5;
    const int bx = lb % nx, by = lb / nx;
    const int n0 = bx * 32, k0 = by * 32;
    const float* W = p.W[seg];
    unsigned short* Wt = p.Wt[seg];
    float gs = 1.f;
    if (seg == 5) gs = 1.f / (1.f + __expf(-p.gate[n0 >> 10]));   // g_head
    const int r = threadIdx.x >> 3, c = (threadIdx.x & 7) * 4;
    const float4 v = *(const float4*)&W[(size_t)(k0 + r) * N + n0 + c];
    T[r][c] = v.x; T[r][c+1] = v.y; T[r][c+2] = v.z; T[r][c+3] = v.w;
    __syncthreads();
    ushort4 o;
    o.x = f2b(T[c][r] * gs); o.y = f2b(T[c+1][r] * gs);
    o.z = f2b(T[c+2][r] * gs); o.w = f2b(T[c+3][r] * gs);
    *(ushort4*)&Wt[(size_t)(n0 + r) * D_MODEL + k0 + c] = o;
}

// ---------------------------------------------------------------------------
// Unnormalized-exp attention: block = (q-tile 64, h, b), 4 waves.
// Logits are bounded (~|L|<10) so p = exp(L) needs no max subtraction;
// masked entries are -inf -> exp = 0. Per kt: {b128 L frags, exp in regs,
// PV MFMA, per-lane denominator adds}. Row sums reduced ONCE at the end.
// LDS 32 KB.
// ---------------------------------------------------------------------------
__global__ __launch_bounds__(256) void attn_e(
    const unsigned short* __restrict__ Lb, const unsigned short* __restrict__ Vb,
    unsigned short* __restrict__ ctx)
{
    const int bx = blockIdx.x;
    const int q1 = bx >> 1;
    const int qt = (bx & 1) ? q1 : (15 - q1);   // heavy/light interleave
    const int h = blockIdx.y, b = blockIdx.z;
    const int tid = threadIdx.x;
    const int lane = tid & 63;
    const int w = tid >> 6;
    const int col = lane & 15, rg = lane >> 4;
    const int q0g = qt * 64;

    __shared__ __align__(16) unsigned short Ls[2][64*64];
    __shared__ __align__(16) unsigned short Vt[2][64*64];
    __shared__ float sums[4][16];

    const int srr = tid >> 3, scp = tid & 7;
    auto issueL = [&](int kt, int buf) {
        const unsigned short* gs = Lb + ((size_t)(b*TQ + q0g)) * NKL + h*MAX_K_LEN + kt*64;
        async_cp16(Ls[buf] + tid*8,        gs + (size_t)srr*NKL + (scp ^ xrow(srr))*8);
        async_cp16(Ls[buf] + 2048 + tid*8, gs + (size_t)(srr+32)*NKL + (scp ^ xrow(srr+32))*8);
    };
    const int vk = tid >> 2, vdc = (tid & 3) * 16;
    const int vkc = vk >> 3, vke = vk & 7;
    u16x8 vr0, vr1;
    auto loadV = [&](int kt) {
        const unsigned short* gv = Vb + ((size_t)(b*TK + kt*64 + vk)) * D_MODEL + h*64 + vdc;
        vr0 = *(const u16x8*)gv;
        vr1 = *(const u16x8*)(gv + 8);
    };
    auto writeV = [&](int buf) {
#pragma unroll
        for (int j = 0; j < 8; ++j) {
            const int d0 = vdc + j, d1 = vdc + 8 + j;
            Vt[buf][d0*64 + (vkc ^ xrow(d0))*8 + vke] = vr0[j];
            Vt[buf][d1*64 + (vkc ^ xrow(d1))*8 + vke] = vr1[j];
        }
    };

    issueL(0, 0);
    loadV(0);
    writeV(0);
    __syncthreads();

    const int lrow = w*16 + col;   // P row owned by this lane (A-frag layout)
    float psum = 0.f;
    f32x4 octx[4];
#pragma unroll
    for (int n = 0; n < 4; ++n) { f32x4 z = {0.f,0.f,0.f,0.f}; octx[n] = z; }

    for (int kt = 0; kt <= qt; ++kt) {
        const int cur = kt & 1;
        if (kt < qt) { issueL(kt + 1, cur ^ 1); loadV(kt + 1); }

#pragma unroll
        for (int s = 0; s < 2; ++s) {
            const bf16x8 lf = *(const bf16x8*)(Ls[cur] + lrow*64 + ((s*4 + rg) ^ xrow(lrow))*8);
            bf16x8 pa;
#pragma unroll
            for (int jj = 0; jj < 8; ++jj) {
                const float e = __expf(b2f((unsigned short)lf[jj]));   // exp(-inf)=0
                psum += e;
                pa[jj] = (short)f2b(e);
            }
#pragma unroll
            for (int n = 0; n < 4; ++n) {
                const int d = n*16 + col;
                const bf16x8 vv = *(const bf16x8*)(Vt[cur] + d*64 + ((s*4 + rg) ^ xrow(d))*8);
                octx[n] = __builtin_amdgcn_mfma_f32_16x16x32_bf16(pa, vv, octx[n], 0, 0, 0);
            }
        }

        if (kt < qt) writeV(cur ^ 1);
        __syncthreads();
    }

    // row-sum reduce (once): lanes sharing col hold partials across k-slots
    psum += __shfl_xor(psum, 16);
    psum += __shfl_xor(psum, 32);
    if (lane < 16) sums[w][lane] = psum;
    __syncthreads();

#pragma unroll
    for (int r = 0; r < 4; ++r) {
        const float sden = sums[w][rg*4 + r];
        const float inv = (sden > 0.f) ? 1.f / sden : 0.f;
        const size_t row = (size_t)(b*TQ + q0g + w*16 + rg*4 + r);
#pragma unroll
        for (int n = 0; n < 4; ++n)
            ctx[row*D_MODEL + h*64 + n*16 + col] = f2b(octx[n][r] * inv);
    }
}

// ---------------------------------------------------------------------------
extern "C" void kernel_launch(void* const* d_in, const int* in_sizes, int n_in,
                              void* d_out, int out_size, void* d_ws, size_t ws_size,
                              hipStream_t stream) {
    const float* x_q  = (const float*)d_in[0];
    const float* x_kv = (const float*)d_in[1];
    const int*   kpm  = (const int*)d_in[2];
    const float* Wq  = (const float*)d_in[3];  const float* bq  = (const float*)d_in[4];
    const float* Wk  = (const float*)d_in[5];  const float* bk  = (const float*)d_in[6];
    const float* Wv  = (const float*)d_in[7];  const float* bv  = (const float*)d_in[8];
    const float* Wo  = (const float*)d_in[9];  const float* bo  = (const float*)d_in[10];
    const float* Ws1 = (const float*)d_in[11]; const float* bs1 = (const float*)d_in[12];
    const float* Ws2 = (const float*)d_in[13]; const float* bs2 = (const float*)d_in[14];
    const float* gate = (const float*)d_in[15];

    char* ws = (char*)d_ws;
    const size_t MB = 1024ull * 1024ull;
    unsigned short* Sb    = (unsigned short*)ws;               // logits L, 64MB region
    unsigned short* xq_b  = (unsigned short*)ws;               // 4MB (dead before Sb)
    unsigned short* xkv_b = (unsigned short*)(ws + 4*MB);      // 4MB
    size_t off = 64*MB;
    unsigned short* Wq_t  = (unsigned short*)(ws + off); off += 2*MB;
    unsigned short* Wk_t  = (unsigned short*)(ws + off); off += 2*MB;
    unsigned short* Wv_t  = (unsigned short*)(ws + off); off += 2*MB;
    unsigned short* Wo_t  = (unsigned short*)(ws + off); off += 2*MB;
    unsigned short* Ws1_t = (unsigned short*)(ws + off); off += 2*MB;
    unsigned short* Ws2_t = (unsigned short*)(ws + off); off += 32*MB;
    unsigned short* Qb    = (unsigned short*)(ws + off); off += 4*MB;
    unsigned short* Kb    = (unsigned short*)(ws + off); off += 4*MB;
    unsigned short* Vb    = (unsigned short*)(ws + off); off += 4*MB;
    unsigned short* hb    = (unsigned short*)(ws + off); off += 4*MB;
    unsigned short* ctxb  = (unsigned short*)(ws + off); off += 4*MB;
    float* bs2g           = (float*)(ws + off); off += 64*1024;

    dim3 blk(256);

    PrepArgs pa;
    pa.xq = x_q; pa.xkv = x_kv; pa.xq_b = xq_b; pa.xkv_b = xkv_b;
    pa.W[0] = Wq;  pa.Wt[0] = Wq_t;  pa.Nw[0] = D_MODEL;
    pa.W[1] = Wk;  pa.Wt[1] = Wk_t;  pa.Nw[1] = D_MODEL;
    pa.W[2] = Wv;  pa.Wt[2] = Wv_t;  pa.Nw[2] = D_MODEL;
    pa.W[3] = Wo;  pa.Wt[3] = Wo_t;  pa.Nw[3] = D_MODEL;
    pa.W[4] = Ws1; pa.Wt[4] = Ws1_t; pa.Nw[4] = D_MODEL;
    pa.W[5] = Ws2; pa.Wt[5] = Ws2_t; pa.Nw[5] = NKL;
    pa.bs2 = bs2; pa.bs2g = bs2g; pa.gate = gate;
    prep_all<<<dim3(25664), blk, 0, stream>>>(pa);

    QkvhArgs qa;
    qa.A[0] = xq_b;  qa.W[0] = Wq_t;  qa.bias[0] = bq;  qa.out[0] = Qb;   // prescaled Q
    qa.A[1] = xkv_b; qa.W[1] = Wk_t;  qa.bias[1] = bk;  qa.out[1] = Kb;
    qa.A[2] = xkv_b; qa.W[2] = Wv_t;  qa.bias[2] = bv;  qa.out[2] = Vb;
    qa.A[3] = xq_b;  qa.W[3] = Ws1_t; qa.bias[3] = bs1; qa.out[3] = hb;
    qa.gate = gate;
    gemm_qkvh_p<<<dim3(128, 1, 4), dim3(256), 0, stream>>>(qa);

    // fused causal logits with kpm+causal mask folded in (1152 blocks,
    // all co-resident at 5 blocks/CU, no spill at (256,4))
    gemm_logits_p<<<dim3(1152), dim3(256), 0, stream>>>(hb, Ws2_t, bs2g, Sb, Qb, Kb, kpm);

    attn_e<<<dim3(TQ/64, N_HEADS, B_SZ), blk, 0, stream>>>(Sb, Vb, ctxb);

    gemm_out_p<<<dim3(8, 16), dim3(256), 0, stream>>>(ctxb, Wo_t, bo, (float*)d_out);
}

// Round 21
// 149.578 us; speedup vs baseline: 1.0144x; 1.0144x over previous
//
#include <hip/hip_runtime.h>
#include <hip/hip_bf16.h>

#define D_MODEL 1024
#define N_HEADS 16
#define MAX_K_LEN 1024
#define B_SZ 2
#define TQ 1024
#define TK 1024
#define M_ROWS 2048
#define NKL 16384

using bf16x8 = __attribute__((ext_vector_type(8))) short;
using f32x4  = __attribute__((ext_vector_type(4))) float;
using u16x8  = __attribute__((ext_vector_type(8))) unsigned short;

__device__ __forceinline__ unsigned short f2b(float f) {
    unsigned u = __float_as_uint(f);
    u = (u + 0x7FFFu + ((u >> 16) & 1u)) >> 16;
    return (unsigned short)u;
}
__device__ __forceinline__ float b2f(unsigned short u) {
    return __uint_as_float(((unsigned)u) << 16);
}

// async global->LDS, 16B per lane (linear LDS dest: wave base + lane*16)
__device__ __forceinline__ void async_cp16(void* lds, const void* g) {
    __builtin_amdgcn_global_load_lds(
        (__attribute__((address_space(1))) void*)(void*)g,
        (__attribute__((address_space(3))) void*)lds, 16, 0, 0);
}

// chunk swizzle for attention LDS tiles (16B-chunk permutation per 128B row)
__device__ __forceinline__ int xrow(int row) {
    return (row & 7) ^ (((row >> 3) & 3) << 1);
}

// ---------------------------------------------------------------------------
// 128x128 ptile core: BK=32, K=1024 (32 K-tiles), 256 threads = 4 waves (2x2),
// wave tile 64x64 (acc 4x4). LDS: 3 buffers x 16 KB = 48 KB -> 3 blocks/CU.
// act: 0 none, 1 exact GELU, 2 per-head Q prescale (* (1-sigmoid(gate_h))/8).
// ---------------------------------------------------------------------------
__device__ __forceinline__ void ptile128_core(
    const unsigned short* __restrict__ A, const unsigned short* __restrict__ Wt,
    const float* __restrict__ bias, unsigned short* __restrict__ C,
    int N, int m0g, int n0g, int act, const float* __restrict__ gate,
    unsigned short* lds)
{
    constexpr int NT = 32;
    const int tid = threadIdx.x;
    const int lane = tid & 63;
    const int fr = lane & 15, rg = lane >> 4;
    const int w = tid >> 6;
    const int wr = w >> 1, wc = w & 1;    // 2M x 2N waves

    const int sr = tid >> 2;              // 0..63
    const int sc = ((tid & 3) ^ ((sr >> 1) & 3)) * 8;
    const unsigned short* gA = A  + (size_t)(m0g + sr) * 1024 + sc;
    const unsigned short* gB = Wt + (size_t)(n0g + sr) * 1024 + sc;

    auto stage = [&](int t) {
        unsigned short* bufA = lds + (t % 3) * 8192;   // 16KB per buffer
        unsigned short* bufB = bufA + 4096;
        const int k0 = t * 32;
        async_cp16(bufA + tid*8,        gA + k0);
        async_cp16(bufA + 2048 + tid*8, gA + (size_t)64*1024 + k0);
        async_cp16(bufB + tid*8,        gB + k0);
        async_cp16(bufB + 2048 + tid*8, gB + (size_t)64*1024 + k0);
    };

    f32x4 acc[4][4];
#pragma unroll
    for (int i = 0; i < 4; ++i)
#pragma unroll
        for (int j = 0; j < 4; ++j) { f32x4 z = {0.f,0.f,0.f,0.f}; acc[i][j] = z; }

    const int fko = (rg ^ ((fr >> 1) & 3)) * 8;

    stage(0); stage(1);
    asm volatile("s_waitcnt vmcnt(4)" ::: "memory");
    __builtin_amdgcn_s_barrier();
    __builtin_amdgcn_sched_barrier(0);

    for (int t = 0; t < NT; ++t) {
        const unsigned short* bufA = lds + (t % 3) * 8192;
        const unsigned short* bufB = bufA + 4096;

        bf16x8 afr[4], bfr[4];
#pragma unroll
        for (int mi = 0; mi < 4; ++mi)
            afr[mi] = *(const bf16x8*)(bufA + (wr*64 + mi*16 + fr)*32 + fko);
#pragma unroll
        for (int ni = 0; ni < 4; ++ni)
            bfr[ni] = *(const bf16x8*)(bufB + (wc*64 + ni*16 + fr)*32 + fko);
        if (t + 2 < NT) stage(t + 2);

        __builtin_amdgcn_s_setprio(1);
#pragma unroll
        for (int mi = 0; mi < 4; ++mi)
#pragma unroll
            for (int ni = 0; ni < 4; ++ni)
                acc[mi][ni] = __builtin_amdgcn_mfma_f32_16x16x32_bf16(
                    afr[mi], bfr[ni], acc[mi][ni], 0, 0, 0);
        __builtin_amdgcn_s_setprio(0);

        if (t < NT - 2)       asm volatile("s_waitcnt vmcnt(4)" ::: "memory");
        else if (t == NT - 2) asm volatile("s_waitcnt vmcnt(0)" ::: "memory");
        __builtin_amdgcn_s_barrier();
        __builtin_amdgcn_sched_barrier(0);
    }

    float qs = 1.f;
    if (act == 2) {   // per-wave head constant: cols n0g+wc*64 .. +63
        const float gg = 1.f / (1.f + __expf(-gate[(n0g + wc*64) >> 6]));
        qs = (1.f - gg) * 0.125f;
    }

    unsigned short* scr = lds + w * 1024;
    float bv[4];
#pragma unroll
    for (int ni = 0; ni < 4; ++ni) bv[ni] = bias[n0g + wc*64 + ni*16 + fr];
    const int ro = lane >> 3;
    const int co = (lane & 7) * 8;
#pragma unroll
    for (int mi = 0; mi < 4; ++mi) {
#pragma unroll
        for (int ni = 0; ni < 4; ++ni)
#pragma unroll
            for (int r = 0; r < 4; ++r) {
                float c = acc[mi][ni][r] + bv[ni];
                if (act == 1) c = 0.5f * c * (1.f + erff(c * 0.70710678118654752f));
                else if (act == 2) c *= qs;
                scr[(rg*4 + r)*64 + ni*16 + fr] = f2b(c);
            }
#pragma unroll
        for (int p = 0; p < 2; ++p) {
            const int row = p*8 + ro;
            const u16x8 v = *(const u16x8*)(scr + row*64 + co);
            *(u16x8*)(C + (size_t)(m0g + wr*64 + mi*16 + row) * N + n0g + wc*64 + co) = v;
        }
    }
}

struct QkvhArgs {
    const unsigned short* A[4];
    const unsigned short* W[4];
    const float* bias[4];
    void* out[4];
    const float* gate;
};

__global__ __launch_bounds__(256, 3) void gemm_qkvh_p(QkvhArgs args) {
    __shared__ __align__(16) unsigned short lds[24576];   // 48 KB
    const int z = blockIdx.z;
    const int m0 = (blockIdx.x >> 3) * 128;
    const int n0 = (blockIdx.x & 7) * 128;
    const int act = (z == 3) ? 1 : ((z == 0) ? 2 : 0);
    ptile128_core(args.A[z], args.W[z], args.bias[z],
                  (unsigned short*)args.out[z], D_MODEL, m0, n0, act, args.gate, lds);
}

// ---------------------------------------------------------------------------
// FUSED causal logits GEMM: L = Qpre@K^T + h@Ws2g^T + bs2g, with kpm+causal
// masking folded into the epilogue (masked -> bf16 -inf). t=0,1 QK tiles,
// t=2..33 synth tiles. 1152 blocks, XCD head-banded. 3-buffer depth-2
// pipeline at (256,3): validated best (R17/R19 150-151us). R18 (256,5)
// spilled; R20 2-buffer/(256,4) lost prefetch depth — both slower.
// ---------------------------------------------------------------------------
__global__ __launch_bounds__(256, 3) void gemm_logits_p(
    const unsigned short* __restrict__ A, const unsigned short* __restrict__ Wt,
    const float* __restrict__ bias, unsigned short* __restrict__ C,
    const unsigned short* __restrict__ Qpre, const unsigned short* __restrict__ Kb,
    const int* __restrict__ kpm)
{
    __shared__ __align__(16) unsigned short lds[24576];   // 48 KB
    constexpr int NT = 34;
    const int bid = blockIdx.x;
    const int xcd = bid & 7;
    const int i = bid >> 3;                    // 0..143
    const int hi = (i >= 72) ? 1 : 0;
    const int head = xcd * 2 + hi;
    const int j = i - hi * 72;                 // 0..71
    int kq, idx;
    if (j < 16)      { kq = 0; idx = j; }
    else if (j < 30) { kq = 1; idx = j - 16; }
    else if (j < 42) { kq = 2; idx = j - 30; }
    else if (j < 52) { kq = 3; idx = j - 42; }
    else if (j < 60) { kq = 4; idx = j - 52; }
    else if (j < 66) { kq = 5; idx = j - 60; }
    else if (j < 70) { kq = 6; idx = j - 66; }
    else             { kq = 7; idx = j - 70; }
    const int b = idx & 1;
    const int rq = kq + (idx >> 1);
    const int m0g = (b * 8 + rq) * 128;        // rows in (b,q) space
    const int n0g = (head * 8 + kq) * 128;     // cols in (h,k) space

    const int tid = threadIdx.x;
    const int lane = tid & 63;
    const int fr = lane & 15, rg = lane >> 4;
    const int w = tid >> 6;
    const int wr = w >> 1, wc = w & 1;

    const int sr = tid >> 2;
    const int sc = ((tid & 3) ^ ((sr >> 1) & 3)) * 8;
    const unsigned short* gA = A  + (size_t)(m0g + sr) * 1024 + sc;
    const unsigned short* gB = Wt + (size_t)(n0g + sr) * 1024 + sc;
    const int q0 = rq * 128, k0a = kq * 128;
    const unsigned short* gA2 = Qpre + (size_t)(b*TQ + q0 + sr) * 1024 + head*64 + sc;
    const unsigned short* gB2 = Kb   + (size_t)(b*TK + k0a + sr) * 1024 + head*64 + sc;

    auto stageQK = [&](int t) {
        unsigned short* bufA = lds + (t % 3) * 8192;
        unsigned short* bufB = bufA + 4096;
        const int k0 = t * 32;
        async_cp16(bufA + tid*8,        gA2 + k0);
        async_cp16(bufA + 2048 + tid*8, gA2 + (size_t)64*1024 + k0);
        async_cp16(bufB + tid*8,        gB2 + k0);
        async_cp16(bufB + 2048 + tid*8, gB2 + (size_t)64*1024 + k0);
    };
    auto stageS = [&](int t) {
        unsigned short* bufA = lds + (t % 3) * 8192;
        unsigned short* bufB = bufA + 4096;
        const int k0 = (t - 2) * 32;
        async_cp16(bufA + tid*8,        gA + k0);
        async_cp16(bufA + 2048 + tid*8, gA + (size_t)64*1024 + k0);
        async_cp16(bufB + tid*8,        gB + k0);
        async_cp16(bufB + 2048 + tid*8, gB + (size_t)64*1024 + k0);
    };

    f32x4 acc[4][4];
#pragma unroll
    for (int ii = 0; ii < 4; ++ii)
#pragma unroll
        for (int jj = 0; jj < 4; ++jj) { f32x4 z = {0.f,0.f,0.f,0.f}; acc[ii][jj] = z; }

    const int fko = (rg ^ ((fr >> 1) & 3)) * 8;

    stageQK(0); stageQK(1);
    asm volatile("s_waitcnt vmcnt(4)" ::: "memory");
    __builtin_amdgcn_s_barrier();
    __builtin_amdgcn_sched_barrier(0);

    for (int t = 0; t < NT; ++t) {
        const unsigned short* bufA = lds + (t % 3) * 8192;
        const unsigned short* bufB = bufA + 4096;

        bf16x8 afr[4], bfr[4];
#pragma unroll
        for (int mi = 0; mi < 4; ++mi)
            afr[mi] = *(const bf16x8*)(bufA + (wr*64 + mi*16 + fr)*32 + fko);
#pragma unroll
        for (int ni = 0; ni < 4; ++ni)
            bfr[ni] = *(const bf16x8*)(bufB + (wc*64 + ni*16 + fr)*32 + fko);
        if (t + 2 < NT) stageS(t + 2);

        __builtin_amdgcn_s_setprio(1);
#pragma unroll
        for (int mi = 0; mi < 4; ++mi)
#pragma unroll
            for (int ni = 0; ni < 4; ++ni)
                acc[mi][ni] = __builtin_amdgcn_mfma_f32_16x16x32_bf16(
                    afr[mi], bfr[ni], acc[mi][ni], 0, 0, 0);
        __builtin_amdgcn_s_setprio(0);

        if (t < NT - 2)       asm volatile("s_waitcnt vmcnt(4)" ::: "memory");
        else if (t == NT - 2) asm volatile("s_waitcnt vmcnt(0)" ::: "memory");
        __builtin_amdgcn_s_barrier();
        __builtin_amdgcn_sched_barrier(0);
    }

    unsigned short* scr = lds + w * 1024;
    float bv[4];
    int kv[4];
#pragma unroll
    for (int ni = 0; ni < 4; ++ni) {
        const int colx = n0g + wc*64 + ni*16 + fr;
        bv[ni] = bias[colx];
        kv[ni] = kpm[b * TK + (colx & 1023)];
    }
    const int ro = lane >> 3;
    const int co = (lane & 7) * 8;
#pragma unroll
    for (int mi = 0; mi < 4; ++mi) {
#pragma unroll
        for (int ni = 0; ni < 4; ++ni) {
            const int k_idx = (n0g + wc*64 + ni*16 + fr) & 1023;
#pragma unroll
            for (int r = 0; r < 4; ++r) {
                const int q_idx = (m0g + wr*64 + mi*16 + rg*4 + r) & 1023;
                const bool ok = (kv[ni] > 0) && (k_idx <= q_idx);
                scr[(rg*4 + r)*64 + ni*16 + fr] =
                    ok ? f2b(acc[mi][ni][r] + bv[ni]) : (unsigned short)0xFF80u;
            }
        }
#pragma unroll
        for (int p = 0; p < 2; ++p) {
            const int row = p*8 + ro;
            const u16x8 v = *(const u16x8*)(scr + row*64 + co);
            *(u16x8*)(C + (size_t)(m0g + wr*64 + mi*16 + row) * NKL + n0g + wc*64 + co) = v;
        }
    }
}

// ---------------------------------------------------------------------------
// Out-proj: ptile128 structure, f32 direct-store epilogue. grid (8,16).
// ---------------------------------------------------------------------------
__global__ __launch_bounds__(256, 3) void gemm_out_p(
    const unsigned short* __restrict__ A, const unsigned short* __restrict__ Wt,
    const float* __restrict__ bias, float* __restrict__ C)
{
    __shared__ __align__(16) unsigned short lds[24576];   // 48 KB
    constexpr int NT = 32;
    const int m0g = blockIdx.y * 128;
    const int n0g = blockIdx.x * 128;

    const int tid = threadIdx.x;
    const int lane = tid & 63;
    const int fr = lane & 15, rg = lane >> 4;
    const int w = tid >> 6;
    const int wr = w >> 1, wc = w & 1;

    const int sr = tid >> 2;
    const int sc = ((tid & 3) ^ ((sr >> 1) & 3)) * 8;
    const unsigned short* gA = A  + (size_t)(m0g + sr) * 1024 + sc;
    const unsigned short* gB = Wt + (size_t)(n0g + sr) * 1024 + sc;

    auto stage = [&](int t) {
        unsigned short* bufA = lds + (t % 3) * 8192;
        unsigned short* bufB = bufA + 4096;
        const int k0 = t * 32;
        async_cp16(bufA + tid*8,        gA + k0);
        async_cp16(bufA + 2048 + tid*8, gA + (size_t)64*1024 + k0);
        async_cp16(bufB + tid*8,        gB + k0);
        async_cp16(bufB + 2048 + tid*8, gB + (size_t)64*1024 + k0);
    };

    f32x4 acc[4][4];
#pragma unroll
    for (int i = 0; i < 4; ++i)
#pragma unroll
        for (int j = 0; j < 4; ++j) { f32x4 z = {0.f,0.f,0.f,0.f}; acc[i][j] = z; }

    const int fko = (rg ^ ((fr >> 1) & 3)) * 8;

    stage(0); stage(1);
    asm volatile("s_waitcnt vmcnt(4)" ::: "memory");
    __builtin_amdgcn_s_barrier();
    __builtin_amdgcn_sched_barrier(0);

    for (int t = 0; t < NT; ++t) {
        const unsigned short* bufA = lds + (t % 3) * 8192;
        const unsigned short* bufB = bufA + 4096;

        bf16x8 afr[4], bfr[4];
#pragma unroll
        for (int mi = 0; mi < 4; ++mi)
            afr[mi] = *(const bf16x8*)(bufA + (wr*64 + mi*16 + fr)*32 + fko);
#pragma unroll
        for (int ni = 0; ni < 4; ++ni)
            bfr[ni] = *(const bf16x8*)(bufB + (wc*64 + ni*16 + fr)*32 + fko);
        if (t + 2 < NT) stage(t + 2);

        __builtin_amdgcn_s_setprio(1);
#pragma unroll
        for (int mi = 0; mi < 4; ++mi)
#pragma unroll
            for (int ni = 0; ni < 4; ++ni)
                acc[mi][ni] = __builtin_amdgcn_mfma_f32_16x16x32_bf16(
                    afr[mi], bfr[ni], acc[mi][ni], 0, 0, 0);
        __builtin_amdgcn_s_setprio(0);

        if (t < NT - 2)       asm volatile("s_waitcnt vmcnt(4)" ::: "memory");
        else if (t == NT - 2) asm volatile("s_waitcnt vmcnt(0)" ::: "memory");
        __builtin_amdgcn_s_barrier();
        __builtin_amdgcn_sched_barrier(0);
    }

#pragma unroll
    for (int ni = 0; ni < 4; ++ni) {
        const int colx = n0g + wc*64 + ni*16 + fr;
        const float bvv = bias[colx];
#pragma unroll
        for (int mi = 0; mi < 4; ++mi)
#pragma unroll
            for (int r = 0; r < 4; ++r) {
                const int row = m0g + wr*64 + mi*16 + rg*4 + r;
                C[(size_t)row * D_MODEL + colx] = acc[mi][ni][r] + bvv;
            }
    }
}

// ---------------------------------------------------------------------------
// fused prep: conversions + transposes + g-scaled Ws2 + g-scaled bs2.
// ---------------------------------------------------------------------------
struct PrepArgs {
    const float* xq; const float* xkv;
    unsigned short* xq_b; unsigned short* xkv_b;
    const float* W[6]; unsigned short* Wt[6]; int Nw[6];
    const float* bs2; float* bs2g; const float* gate;
};

__global__ __launch_bounds__(256) void prep_all(PrepArgs p) {
    __shared__ float T[32][33];
    int id = blockIdx.x;
    if (id < 4096) {
        const float* src = (id < 2048) ? p.xq : p.xkv;
        unsigned short* dst = (id < 2048) ? p.xq_b : p.xkv_b;
        const int i = (id & 2047) * 256 + threadIdx.x;
        const float4 v = ((const float4*)src)[i];
        ushort4 o; o.x = f2b(v.x); o.y = f2b(v.y); o.z = f2b(v.z); o.w = f2b(v.w);
        ((ushort4*)dst)[i] = o;
        return;
    }
    if (id >= 25600) {   // bs2g = sigmoid(gate) * bs2
        const int i = (id - 25600) * 256 + threadIdx.x;
        const float gg = 1.f / (1.f + __expf(-p.gate[i >> 10]));
        p.bs2g[i] = gg * p.bs2[i];
        return;
    }
    id -= 4096;
    int seg, lb;
    if (id < 5120) { seg = id >> 10; lb = id & 1023; }
    else           { seg = 5;        lb = id - 5120; }
    const int N = p.Nw[seg];
    const int nx = N >> 5;
    const int bx = lb % nx, by = lb / nx;
    const int n0 = bx * 32, k0 = by * 32;
    const float* W = p.W[seg];
    unsigned short* Wt = p.Wt[seg];
    float gs = 1.f;
    if (seg == 5) gs = 1.f / (1.f + __expf(-p.gate[n0 >> 10]));   // g_head
    const int r = threadIdx.x >> 3, c = (threadIdx.x & 7) * 4;
    const float4 v = *(const float4*)&W[(size_t)(k0 + r) * N + n0 + c];
    T[r][c] = v.x; T[r][c+1] = v.y; T[r][c+2] = v.z; T[r][c+3] = v.w;
    __syncthreads();
    ushort4 o;
    o.x = f2b(T[c][r] * gs); o.y = f2b(T[c+1][r] * gs);
    o.z = f2b(T[c+2][r] * gs); o.w = f2b(T[c+3][r] * gs);
    *(ushort4*)&Wt[(size_t)(n0 + r) * D_MODEL + k0 + c] = o;
}

// ---------------------------------------------------------------------------
// Unnormalized-exp attention: block = (q-tile 64, h, b), 4 waves.
// Logits are bounded (~|L|<10) so p = exp(L) needs no max subtraction;
// masked entries are -inf -> exp = 0. Per kt: {b128 L frags, exp in regs,
// PV MFMA, per-lane denominator adds}. Row sums reduced ONCE at the end.
// LDS 32 KB.
// ---------------------------------------------------------------------------
__global__ __launch_bounds__(256) void attn_e(
    const unsigned short* __restrict__ Lb, const unsigned short* __restrict__ Vb,
    unsigned short* __restrict__ ctx)
{
    const int bx = blockIdx.x;
    const int q1 = bx >> 1;
    const int qt = (bx & 1) ? q1 : (15 - q1);   // heavy/light interleave
    const int h = blockIdx.y, b = blockIdx.z;
    const int tid = threadIdx.x;
    const int lane = tid & 63;
    const int w = tid >> 6;
    const int col = lane & 15, rg = lane >> 4;
    const int q0g = qt * 64;

    __shared__ __align__(16) unsigned short Ls[2][64*64];
    __shared__ __align__(16) unsigned short Vt[2][64*64];
    __shared__ float sums[4][16];

    const int srr = tid >> 3, scp = tid & 7;
    auto issueL = [&](int kt, int buf) {
        const unsigned short* gs = Lb + ((size_t)(b*TQ + q0g)) * NKL + h*MAX_K_LEN + kt*64;
        async_cp16(Ls[buf] + tid*8,        gs + (size_t)srr*NKL + (scp ^ xrow(srr))*8);
        async_cp16(Ls[buf] + 2048 + tid*8, gs + (size_t)(srr+32)*NKL + (scp ^ xrow(srr+32))*8);
    };
    const int vk = tid >> 2, vdc = (tid & 3) * 16;
    const int vkc = vk >> 3, vke = vk & 7;
    u16x8 vr0, vr1;
    auto loadV = [&](int kt) {
        const unsigned short* gv = Vb + ((size_t)(b*TK + kt*64 + vk)) * D_MODEL + h*64 + vdc;
        vr0 = *(const u16x8*)gv;
        vr1 = *(const u16x8*)(gv + 8);
    };
    auto writeV = [&](int buf) {
#pragma unroll
        for (int j = 0; j < 8; ++j) {
            const int d0 = vdc + j, d1 = vdc + 8 + j;
            Vt[buf][d0*64 + (vkc ^ xrow(d0))*8 + vke] = vr0[j];
            Vt[buf][d1*64 + (vkc ^ xrow(d1))*8 + vke] = vr1[j];
        }
    };

    issueL(0, 0);
    loadV(0);
    writeV(0);
    __syncthreads();

    const int lrow = w*16 + col;   // P row owned by this lane (A-frag layout)
    float psum = 0.f;
    f32x4 octx[4];
#pragma unroll
    for (int n = 0; n < 4; ++n) { f32x4 z = {0.f,0.f,0.f,0.f}; octx[n] = z; }

    for (int kt = 0; kt <= qt; ++kt) {
        const int cur = kt & 1;
        if (kt < qt) { issueL(kt + 1, cur ^ 1); loadV(kt + 1); }

#pragma unroll
        for (int s = 0; s < 2; ++s) {
            const bf16x8 lf = *(const bf16x8*)(Ls[cur] + lrow*64 + ((s*4 + rg) ^ xrow(lrow))*8);
            bf16x8 pa;
#pragma unroll
            for (int jj = 0; jj < 8; ++jj) {
                const float e = __expf(b2f((unsigned short)lf[jj]));   // exp(-inf)=0
                psum += e;
                pa[jj] = (short)f2b(e);
            }
#pragma unroll
            for (int n = 0; n < 4; ++n) {
                const int d = n*16 + col;
                const bf16x8 vv = *(const bf16x8*)(Vt[cur] + d*64 + ((s*4 + rg) ^ xrow(d))*8);
                octx[n] = __builtin_amdgcn_mfma_f32_16x16x32_bf16(pa, vv, octx[n], 0, 0, 0);
            }
        }

        if (kt < qt) writeV(cur ^ 1);
        __syncthreads();
    }

    // row-sum reduce (once): lanes sharing col hold partials across k-slots
    psum += __shfl_xor(psum, 16);
    psum += __shfl_xor(psum, 32);
    if (lane < 16) sums[w][lane] = psum;
    __syncthreads();

#pragma unroll
    for (int r = 0; r < 4; ++r) {
        const float sden = sums[w][rg*4 + r];
        const float inv = (sden > 0.f) ? 1.f / sden : 0.f;
        const size_t row = (size_t)(b*TQ + q0g + w*16 + rg*4 + r);
#pragma unroll
        for (int n = 0; n < 4; ++n)
            ctx[row*D_MODEL + h*64 + n*16 + col] = f2b(octx[n][r] * inv);
    }
}

// ---------------------------------------------------------------------------
extern "C" void kernel_launch(void* const* d_in, const int* in_sizes, int n_in,
                              void* d_out, int out_size, void* d_ws, size_t ws_size,
                              hipStream_t stream) {
    const float* x_q  = (const float*)d_in[0];
    const float* x_kv = (const float*)d_in[1];
    const int*   kpm  = (const int*)d_in[2];
    const float* Wq  = (const float*)d_in[3];  const float* bq  = (const float*)d_in[4];
    const float* Wk  = (const float*)d_in[5];  const float* bk  = (const float*)d_in[6];
    const float* Wv  = (const float*)d_in[7];  const float* bv  = (const float*)d_in[8];
    const float* Wo  = (const float*)d_in[9];  const float* bo  = (const float*)d_in[10];
    const float* Ws1 = (const float*)d_in[11]; const float* bs1 = (const float*)d_in[12];
    const float* Ws2 = (const float*)d_in[13]; const float* bs2 = (const float*)d_in[14];
    const float* gate = (const float*)d_in[15];

    char* ws = (char*)d_ws;
    const size_t MB = 1024ull * 1024ull;
    unsigned short* Sb    = (unsigned short*)ws;               // logits L, 64MB region
    unsigned short* xq_b  = (unsigned short*)ws;               // 4MB (dead before Sb)
    unsigned short* xkv_b = (unsigned short*)(ws + 4*MB);      // 4MB
    size_t off = 64*MB;
    unsigned short* Wq_t  = (unsigned short*)(ws + off); off += 2*MB;
    unsigned short* Wk_t  = (unsigned short*)(ws + off); off += 2*MB;
    unsigned short* Wv_t  = (unsigned short*)(ws + off); off += 2*MB;
    unsigned short* Wo_t  = (unsigned short*)(ws + off); off += 2*MB;
    unsigned short* Ws1_t = (unsigned short*)(ws + off); off += 2*MB;
    unsigned short* Ws2_t = (unsigned short*)(ws + off); off += 32*MB;
    unsigned short* Qb    = (unsigned short*)(ws + off); off += 4*MB;
    unsigned short* Kb    = (unsigned short*)(ws + off); off += 4*MB;
    unsigned short* Vb    = (unsigned short*)(ws + off); off += 4*MB;
    unsigned short* hb    = (unsigned short*)(ws + off); off += 4*MB;
    unsigned short* ctxb  = (unsigned short*)(ws + off); off += 4*MB;
    float* bs2g           = (float*)(ws + off); off += 64*1024;

    dim3 blk(256);

    PrepArgs pa;
    pa.xq = x_q; pa.xkv = x_kv; pa.xq_b = xq_b; pa.xkv_b = xkv_b;
    pa.W[0] = Wq;  pa.Wt[0] = Wq_t;  pa.Nw[0] = D_MODEL;
    pa.W[1] = Wk;  pa.Wt[1] = Wk_t;  pa.Nw[1] = D_MODEL;
    pa.W[2] = Wv;  pa.Wt[2] = Wv_t;  pa.Nw[2] = D_MODEL;
    pa.W[3] = Wo;  pa.Wt[3] = Wo_t;  pa.Nw[3] = D_MODEL;
    pa.W[4] = Ws1; pa.Wt[4] = Ws1_t; pa.Nw[4] = D_MODEL;
    pa.W[5] = Ws2; pa.Wt[5] = Ws2_t; pa.Nw[5] = NKL;
    pa.bs2 = bs2; pa.bs2g = bs2g; pa.gate = gate;
    prep_all<<<dim3(25664), blk, 0, stream>>>(pa);

    QkvhArgs qa;
    qa.A[0] = xq_b;  qa.W[0] = Wq_t;  qa.bias[0] = bq;  qa.out[0] = Qb;   // prescaled Q
    qa.A[1] = xkv_b; qa.W[1] = Wk_t;  qa.bias[1] = bk;  qa.out[1] = Kb;
    qa.A[2] = xkv_b; qa.W[2] = Wv_t;  qa.bias[2] = bv;  qa.out[2] = Vb;
    qa.A[3] = xq_b;  qa.W[3] = Ws1_t; qa.bias[3] = bs1; qa.out[3] = hb;
    qa.gate = gate;
    gemm_qkvh_p<<<dim3(128, 1, 4), dim3(256), 0, stream>>>(qa);

    // fused causal logits with kpm+causal mask folded in (1152 blocks)
    gemm_logits_p<<<dim3(1152), dim3(256), 0, stream>>>(hb, Ws2_t, bs2g, Sb, Qb, Kb, kpm);

    attn_e<<<dim3(TQ/64, N_HEADS, B_SZ), blk, 0, stream>>>(Sb, Vb, ctxb);

    gemm_out_p<<<dim3(8, 16), dim3(256), 0, stream>>>(ctxb, Wo_t, bo, (float*)d_out);
}